// Round 1
// baseline (1167.041 us; speedup 1.0000x reference)
//
#include <hip/hip_runtime.h>
#include <hip/hip_bf16.h>
#include <math.h>

// Problem constants: B=4, N=4096, D=1024, H=16, HD=64, MLP=4096
#define NTOK   16384      // B*N rows
#define DMODEL 1024
#define DMLP   4096

typedef __attribute__((ext_vector_type(8))) __bf16  bf16x8;
typedef __attribute__((ext_vector_type(4))) float   f32x4;
typedef __attribute__((ext_vector_type(8))) unsigned short u16x8;

__device__ __forceinline__ float bf2f(unsigned short u) {
  unsigned int i = ((unsigned int)u) << 16;
  return __builtin_bit_cast(float, i);
}
__device__ __forceinline__ unsigned short f2bf(float f) {
  unsigned int u = __builtin_bit_cast(unsigned int, f);
  unsigned int r = 0x7fffu + ((u >> 16) & 1u);
  return (unsigned short)((u + r) >> 16);
}

__device__ __forceinline__ void gload_lds16(const void* g, void* l) {
  __builtin_amdgcn_global_load_lds(
      (const __attribute__((address_space(1))) unsigned int*)g,
      (__attribute__((address_space(3))) unsigned int*)l, 16, 0, 0);
}

// ---------------- weight transpose + f32->bf16 -------------------------------
// W: [K][N] f32  ->  Wt: [N][K] bf16   (B^T layout for the GEMM)
__global__ void __launch_bounds__(256) transpose_cvt(
    const float* __restrict__ W, unsigned short* __restrict__ Wt, int K, int N)
{
  __shared__ float tile[32][33];
  const int kb = blockIdx.y * 32, nb = blockIdx.x * 32;
  const int tx = threadIdx.x & 31, ty = threadIdx.x >> 5;   // 32 x 8
#pragma unroll
  for (int j = 0; j < 32; j += 8)
    tile[ty + j][tx] = W[(size_t)(kb + ty + j) * N + nb + tx];
  __syncthreads();
#pragma unroll
  for (int j = 0; j < 32; j += 8)
    Wt[(size_t)(nb + ty + j) * K + kb + tx] = f2bf(tile[tx][ty + j]);
}

__global__ void __launch_bounds__(256) concat_bias(
    const float* __restrict__ bq, const float* __restrict__ bk,
    const float* __restrict__ bv, float* __restrict__ bqkv)
{
  const int i = blockIdx.x * 256 + threadIdx.x;   // grid 12 -> 3072
  float v;
  if (i < 1024)      v = bq[i];
  else if (i < 2048) v = bk[i - 1024];
  else               v = bv[i - 2048];
  bqkv[i] = v;
}

// ---------------- LayerNorm (biased var, eps=1e-5) -> bf16 -------------------
__global__ void __launch_bounds__(256) ln_kernel(
    const float* __restrict__ x, const float* __restrict__ w,
    const float* __restrict__ b, unsigned short* __restrict__ out)
{
  const int row = blockIdx.x;
  const int t = threadIdx.x;
  const float4 v = ((const float4*)(x + (size_t)row * DMODEL))[t];
  float s  = v.x + v.y + v.z + v.w;
  float s2 = v.x*v.x + v.y*v.y + v.z*v.z + v.w*v.w;
#pragma unroll
  for (int o = 1; o < 64; o <<= 1) { s += __shfl_xor(s, o); s2 += __shfl_xor(s2, o); }
  __shared__ float red[8];
  const int wid = t >> 6;
  if ((t & 63) == 0) { red[wid] = s; red[4 + wid] = s2; }
  __syncthreads();
  s  = red[0] + red[1] + red[2] + red[3];
  s2 = red[4] + red[5] + red[6] + red[7];
  const float mean = s * (1.f / DMODEL);
  const float rstd = rsqrtf(s2 * (1.f / DMODEL) - mean * mean + 1e-5f);
  const float4 wv = ((const float4*)w)[t];
  const float4 bv = ((const float4*)b)[t];
  ushort4 o;
  o.x = f2bf((v.x - mean) * rstd * wv.x + bv.x);
  o.y = f2bf((v.y - mean) * rstd * wv.y + bv.y);
  o.z = f2bf((v.z - mean) * rstd * wv.z + bv.z);
  o.w = f2bf((v.w - mean) * rstd * wv.w + bv.w);
  ((ushort4*)(out + (size_t)row * DMODEL))[t] = o;
}

// ---------------- bf16 MFMA GEMM, 128x128 tile, BK=64 (m97 structure) --------
// A: [M][K] bf16 ; Bt: [N][K] bf16 ; epilogue per MODE.
// MODE 0: +bias, elu+1 on cols<2048, store bf16   (QKV)
// MODE 1: +bias, +addsrc(f32), store f32          (WO / PROJ residual)
// MODE 2: +bias, exact gelu, store bf16           (FC)
template<int MODE>
__global__ void __launch_bounds__(256) gemm_bt(
    const unsigned short* __restrict__ A, const unsigned short* __restrict__ Bt,
    int M, int N, int K,
    const float* __restrict__ bias, const float* __restrict__ addsrc,
    void* __restrict__ outp)
{
  __shared__ unsigned short sA[128 * 64];
  __shared__ unsigned short sB[128 * 64];
  const int t = threadIdx.x;
  const int lane = t & 63;
  const int tiles_n = N >> 7;
  const int m0 = (blockIdx.x / tiles_n) << 7;
  const int n0 = (blockIdx.x % tiles_n) << 7;
  const int wid = t >> 6;
  const int wr = (wid >> 1) << 6;   // wave row offset (0/64)
  const int wc = (wid & 1) << 6;    // wave col offset (0/64)

  f32x4 acc[4][4] = {};

  // staging: thread t loads 16B; LDS linear [row][k] with BK=64
  const int srow  = t >> 3;          // 0..31
  const int skoff = (t & 7) << 3;    // 0..56
  const unsigned short* Abase = A  + (size_t)(m0 + srow) * K + skoff;
  const unsigned short* Bbase = Bt + (size_t)(n0 + srow) * K + skoff;
  unsigned short* sAp = sA + t * 8;
  unsigned short* sBp = sB + t * 8;

  const int fr = lane & 15;          // fragment row/col
  const int fk = (lane >> 4) << 3;   // k-base 0/8/16/24

  for (int k0 = 0; k0 < K; k0 += 64) {
    __syncthreads();
#pragma unroll
    for (int j = 0; j < 4; ++j) {
      gload_lds16(Abase + (size_t)(j * 32) * K + k0, sAp + j * 32 * 64);
      gload_lds16(Bbase + (size_t)(j * 32) * K + k0, sBp + j * 32 * 64);
    }
    __syncthreads();
#pragma unroll
    for (int ks = 0; ks < 2; ++ks) {
      bf16x8 af[4], bfr[4];
#pragma unroll
      for (int i = 0; i < 4; ++i) {
        af[i]  = *(const bf16x8*)(sA + (wr + i * 16 + fr) * 64 + ks * 32 + fk);
        bfr[i] = *(const bf16x8*)(sB + (wc + i * 16 + fr) * 64 + ks * 32 + fk);
      }
#pragma unroll
      for (int i = 0; i < 4; ++i)
#pragma unroll
        for (int j = 0; j < 4; ++j)
          acc[i][j] = __builtin_amdgcn_mfma_f32_16x16x32_bf16(af[i], bfr[j], acc[i][j], 0, 0, 0);
    }
  }

  // epilogue: C[row=(lane>>4)*4+r][col=lane&15] per 16x16 fragment
  const int crow0 = m0 + wr + ((lane >> 4) << 2);
  const int ccol0 = n0 + wc + fr;
#pragma unroll
  for (int j = 0; j < 4; ++j) {
    const int col = ccol0 + j * 16;
    const float bc = bias[col];
#pragma unroll
    for (int i = 0; i < 4; ++i) {
#pragma unroll
      for (int r = 0; r < 4; ++r) {
        const int row = crow0 + i * 16 + r;
        float v = acc[i][j][r] + bc;
        if (MODE == 0) {
          if (col < 2048) v = (v > 0.f) ? (v + 1.f) : expf(v);  // elu(x)+1
          ((unsigned short*)outp)[(size_t)row * N + col] = f2bf(v);
        } else if (MODE == 1) {
          v += addsrc[(size_t)row * N + col];
          ((float*)outp)[(size_t)row * N + col] = v;
        } else {
          v = 0.5f * v * (1.f + erff(v * 0.70710678118654752f)); // exact gelu
          ((unsigned short*)outp)[(size_t)row * N + col] = f2bf(v);
        }
      }
    }
  }
}

// ---------------- per-position head-mix "attention" --------------------------
// qkv row layout: [0,1024)=fq(h*64+d), [1024,2048)=fk, [2048,3072)=v
// one 64-lane wave per position; lane owns column e of kv / output
__global__ void __launch_bounds__(256) attn_kernel(
    const unsigned short* __restrict__ qkv, unsigned short* __restrict__ attn)
{
  __shared__ float sqk[4][2048];    // per wave: fq[1024] then fk[1024] as f32
  const int t = threadIdx.x, lane = t & 63, wid = t >> 6;
  const int p = blockIdx.x * 4 + wid;
  const unsigned short* row = qkv + (size_t)p * 3072;
  float* s = sqk[wid];
#pragma unroll
  for (int c = 0; c < 4; ++c) {
    const int idx = c * 512 + lane * 8;
    u16x8 v8 = *(const u16x8*)(row + idx);
#pragma unroll
    for (int u = 0; u < 8; ++u) s[idx + u] = bf2f(v8[u]);
  }
  __syncthreads();

  float vf[16];
#pragma unroll
  for (int g = 0; g < 16; ++g) vf[g] = bf2f(row[2048 + g * 64 + lane]); // v[:,e]

  float kv[64] = {};   // kv[d][e] for my e
  float ks[64] = {};   // k_sum[d] (uniform, computed per-lane)
  const float* FK = s + 1024;
#pragma unroll 2
  for (int h = 0; h < 16; ++h) {
    const float vfh = vf[h];
#pragma unroll
    for (int dq = 0; dq < 16; ++dq) {
      const float4 f = *(const float4*)(FK + h * 64 + dq * 4);
      kv[dq*4+0] += f.x * vfh; ks[dq*4+0] += f.x;
      kv[dq*4+1] += f.y * vfh; ks[dq*4+1] += f.y;
      kv[dq*4+2] += f.z * vfh; ks[dq*4+2] += f.z;
      kv[dq*4+3] += f.w * vfh; ks[dq*4+3] += f.w;
    }
  }
  unsigned short* orow = attn + (size_t)p * 1024;
#pragma unroll 2
  for (int h = 0; h < 16; ++h) {
    float aq = 0.f, ak = 0.f;
#pragma unroll
    for (int dq = 0; dq < 16; ++dq) {
      const float4 f = *(const float4*)(s + h * 64 + dq * 4);
      aq += f.x*kv[dq*4+0] + f.y*kv[dq*4+1] + f.z*kv[dq*4+2] + f.w*kv[dq*4+3];
      ak += f.x*ks[dq*4+0] + f.y*ks[dq*4+1] + f.z*ks[dq*4+2] + f.w*ks[dq*4+3];
    }
    orow[h * 64 + lane] = f2bf(aq / (ak + 1e-6f));
  }
}

// ---------------- launch ----------------------------------------------------
extern "C" void kernel_launch(void* const* d_in, const int* in_sizes, int n_in,
                              void* d_out, int out_size, void* d_ws, size_t ws_size,
                              hipStream_t stream) {
  const float* q_x    = (const float*)d_in[0];
  const float* ln1_w  = (const float*)d_in[1];
  const float* ln1_b  = (const float*)d_in[2];
  const float* wq     = (const float*)d_in[3];
  const float* bq     = (const float*)d_in[4];
  const float* wk     = (const float*)d_in[5];
  const float* bk     = (const float*)d_in[6];
  const float* wv     = (const float*)d_in[7];
  const float* bv     = (const float*)d_in[8];
  const float* wo     = (const float*)d_in[9];
  const float* bo     = (const float*)d_in[10];
  const float* ln2_w  = (const float*)d_in[11];
  const float* ln2_b  = (const float*)d_in[12];
  const float* fc_w   = (const float*)d_in[13];
  const float* fc_b   = (const float*)d_in[14];
  const float* proj_w = (const float*)d_in[15];
  const float* proj_b = (const float*)d_in[16];

  char* ws = (char*)d_ws;
  // ws layout (bytes):
  unsigned short* wqkv_t = (unsigned short*)(ws + 0);          //  6,291,456  [3072][1024]
  unsigned short* wo_t   = (unsigned short*)(ws + 6291456);    //  2,097,152  [1024][1024]
  unsigned short* fc_t   = (unsigned short*)(ws + 8388608);    //  8,388,608  [4096][1024]
  unsigned short* proj_t = (unsigned short*)(ws + 16777216);   //  8,388,608  [1024][4096]
  float*          bqkv   = (float*)(ws + 25165824);            //     12,288  [3072]
  unsigned short* xn     = (unsigned short*)(ws + 25178112);   // 33,554,432  [16384][1024] xn/attn/h_in
  unsigned short* big    = (unsigned short*)(ws + 58732544);   //134,217,728  qkv [16384][3072] / hg [16384][4096]
  float*          xres   = (float*)d_out;                      // x lives in d_out

  dim3 blk(256);
  transpose_cvt<<<dim3(32, 32),  blk, 0, stream>>>(wq,     wqkv_t,           1024, 1024);
  transpose_cvt<<<dim3(32, 32),  blk, 0, stream>>>(wk,     wqkv_t + 1048576, 1024, 1024);
  transpose_cvt<<<dim3(32, 32),  blk, 0, stream>>>(wv,     wqkv_t + 2097152, 1024, 1024);
  transpose_cvt<<<dim3(32, 32),  blk, 0, stream>>>(wo,     wo_t,             1024, 1024);
  transpose_cvt<<<dim3(128, 32), blk, 0, stream>>>(fc_w,   fc_t,             1024, 4096);
  transpose_cvt<<<dim3(32, 128), blk, 0, stream>>>(proj_w, proj_t,           4096, 1024);
  concat_bias<<<12, blk, 0, stream>>>(bq, bk, bv, bqkv);

  ln_kernel<<<NTOK, blk, 0, stream>>>(q_x, ln1_w, ln1_b, xn);
  gemm_bt<0><<<128 * 24, blk, 0, stream>>>(xn, wqkv_t, NTOK, 3072, 1024, bqkv, nullptr, big);
  attn_kernel<<<NTOK / 4, blk, 0, stream>>>(big, xn);
  gemm_bt<1><<<128 * 8,  blk, 0, stream>>>(xn, wo_t,   NTOK, 1024, 1024, bo, q_x, xres);
  ln_kernel<<<NTOK, blk, 0, stream>>>(xres, ln2_w, ln2_b, xn);
  gemm_bt<2><<<128 * 32, blk, 0, stream>>>(xn, fc_t,   NTOK, 4096, 1024, fc_b, nullptr, big);
  gemm_bt<1><<<128 * 8,  blk, 0, stream>>>(big, proj_t, NTOK, 1024, 4096, proj_b, xres, xres);
}

// Round 2
// 955.130 us; speedup vs baseline: 1.2219x; 1.2219x over previous
//
#include <hip/hip_runtime.h>
#include <hip/hip_bf16.h>
#include <math.h>

// Problem constants: B=4, N=4096, D=1024, H=16, HD=64, MLP=4096
#define NTOK   16384      // B*N rows
#define DMODEL 1024
#define DMLP   4096

typedef __attribute__((ext_vector_type(8))) __bf16  bf16x8;
typedef __attribute__((ext_vector_type(4))) float   f32x4;
typedef __attribute__((ext_vector_type(8))) unsigned short u16x8;

__device__ __forceinline__ float bf2f(unsigned short u) {
  unsigned int i = ((unsigned int)u) << 16;
  return __builtin_bit_cast(float, i);
}
__device__ __forceinline__ unsigned short f2bf(float f) {
  unsigned int u = __builtin_bit_cast(unsigned int, f);
  unsigned int r = 0x7fffu + ((u >> 16) & 1u);
  return (unsigned short)((u + r) >> 16);
}

__device__ __forceinline__ void gload_lds16(const void* g, void* l) {
  __builtin_amdgcn_global_load_lds(
      (const __attribute__((address_space(1))) unsigned int*)g,
      (__attribute__((address_space(3))) unsigned int*)l, 16, 0, 0);
}

__device__ __forceinline__ float gelu_f(float x) {
  // tanh-approx gelu = x * sigmoid(2*0.797885*(x + 0.044715 x^3)); |err| < 4e-4
  float u = 1.5957691216057308f * (x + 0.044715f * x * x * x);
  return x / (1.f + __expf(-u));
}

// ---------------- weight transpose + f32->bf16 -------------------------------
__global__ void __launch_bounds__(256) transpose_cvt(
    const float* __restrict__ W, unsigned short* __restrict__ Wt, int K, int N)
{
  __shared__ float tile[32][33];
  const int kb = blockIdx.y * 32, nb = blockIdx.x * 32;
  const int tx = threadIdx.x & 31, ty = threadIdx.x >> 5;   // 32 x 8
#pragma unroll
  for (int j = 0; j < 32; j += 8)
    tile[ty + j][tx] = W[(size_t)(kb + ty + j) * N + nb + tx];
  __syncthreads();
#pragma unroll
  for (int j = 0; j < 32; j += 8)
    Wt[(size_t)(nb + ty + j) * K + kb + tx] = f2bf(tile[tx][ty + j]);
}

__global__ void __launch_bounds__(256) concat_bias(
    const float* __restrict__ bq, const float* __restrict__ bk,
    const float* __restrict__ bv, float* __restrict__ bqkv)
{
  const int i = blockIdx.x * 256 + threadIdx.x;
  float v;
  if (i < 1024)      v = bq[i];
  else if (i < 2048) v = bk[i - 1024];
  else               v = bv[i - 2048];
  bqkv[i] = v;
}

// ---------------- LayerNorm (biased var, eps=1e-5) -> bf16 -------------------
__global__ void __launch_bounds__(256) ln_kernel(
    const float* __restrict__ x, const float* __restrict__ w,
    const float* __restrict__ b, unsigned short* __restrict__ out)
{
  const int row = blockIdx.x;
  const int t = threadIdx.x;
  const float4 v = ((const float4*)(x + (size_t)row * DMODEL))[t];
  float s  = v.x + v.y + v.z + v.w;
  float s2 = v.x*v.x + v.y*v.y + v.z*v.z + v.w*v.w;
#pragma unroll
  for (int o = 1; o < 64; o <<= 1) { s += __shfl_xor(s, o); s2 += __shfl_xor(s2, o); }
  __shared__ float red[8];
  const int wid = t >> 6;
  if ((t & 63) == 0) { red[wid] = s; red[4 + wid] = s2; }
  __syncthreads();
  s  = red[0] + red[1] + red[2] + red[3];
  s2 = red[4] + red[5] + red[6] + red[7];
  const float mean = s * (1.f / DMODEL);
  const float rstd = rsqrtf(s2 * (1.f / DMODEL) - mean * mean + 1e-5f);
  const float4 wv = ((const float4*)w)[t];
  const float4 bv = ((const float4*)b)[t];
  ushort4 o;
  o.x = f2bf((v.x - mean) * rstd * wv.x + bv.x);
  o.y = f2bf((v.y - mean) * rstd * wv.y + bv.y);
  o.z = f2bf((v.z - mean) * rstd * wv.z + bv.z);
  o.w = f2bf((v.w - mean) * rstd * wv.w + bv.w);
  ((ushort4*)(out + (size_t)row * DMODEL))[t] = o;
}

// ---------------- 256x256 8-phase bf16 MFMA GEMM (T1+T2+T3+T4+T5) ------------
// A: [M][K] bf16 ; Bt: [N][K] bf16. 512 thr = 8 waves (2M x 4N). BK=64.
// LDS 128KB: A[buf][half] = (buf*2+h)*8192 shorts; B at +32768. Half = 128 rows x 64k.
// Swizzle: 16B chunk kc stored at kc^(row&7) (applied on global src; LDS linear).
// Phase schedule per iteration r (computes kt=2r in buf0 ph0-3, kt=2r+1 in buf1 ph4-7):
//   ph0: LDA(b0,mh0)+LDB(b0,nh0) | stage A.h0->buf1(kt+1)  | bar | 16 MFMA | bar
//   ph1: LDB(b0,nh1)             | stage A.h1->buf1(kt+1)  | ...
//   ph2: LDA(b0,mh1)             | stage B.h0->buf0(kt+2)  | ...
//   ph3: (regs)                  | stage B.h1->buf0(kt+2)  | bar | MFMA | vmcnt(4) | bar
//   ph4: LDA(b1,mh0)+LDB(b1,nh0) | stage A.h0->buf0(kt+2)  | ...
//   ph5: LDB(b1,nh1)             | stage A.h1->buf0(kt+2)  | ...
//   ph6: LDA(b1,mh1)             | stage B.h0->buf1(kt+3)  | ...
//   ph7: (regs)                  | stage B.h1->buf1(kt+3)  | bar | MFMA | vmcnt(4) | bar
// Invariants: every region's overwrite phase > its last-read phase (barrier between);
// vmcnt(4) leaves only the 2 newest half-tiles pending, which are never the ones
// read next. Last iteration skips stages and drains vmcnt(0).
template<int MODE>
__global__ void __launch_bounds__(512, 2) gemm256(
    const unsigned short* __restrict__ A, const unsigned short* __restrict__ Bt,
    int M, int N, int K,
    const float* __restrict__ bias, const float* __restrict__ addsrc,
    void* __restrict__ outp)
{
  extern __shared__ unsigned short lds[];   // 65536 shorts = 128 KiB
  const int t    = threadIdx.x;
  const int lane = t & 63;
  const int wid  = t >> 6;
  const int wm   = wid >> 2;     // 0..1
  const int wn   = wid & 3;      // 0..3
  const int fr   = lane & 15;
  const int hi   = lane >> 4;    // 0..3

  // XCD-aware block swizzle (nwg % 8 == 0 for all our shapes)
  const int tiles_n = N >> 8;
  const int nwg = (int)gridDim.x;
  const int cpx = nwg >> 3;
  const int bid = (int)blockIdx.x;
  const int wg  = (bid & 7) * cpx + (bid >> 3);
  const int m0 = (wg / tiles_n) << 8;
  const int n0 = (wg % tiles_n) << 8;

  // staging: thread covers chunks n=t (row t>>3) and n=512+t (row +64)
  const int srow0 = t >> 3;
  const int srow1 = srow0 + 64;
  const int sc    = t & 7;
  const size_t soff0 = (size_t)srow0 * K + (size_t)((sc ^ (srow0 & 7)) << 3);
  const size_t soff1 = (size_t)srow1 * K + (size_t)((sc ^ (srow1 & 7)) << 3);
  const unsigned short* Ag = A  + (size_t)m0 * K;
  const unsigned short* Bg = Bt + (size_t)n0 * K;

  // ds-read swizzled chunk slots (row%8 == fr%8 for all frag rows)
  const int pc0 = hi ^ (fr & 7);         // ks=0 chunk
  const int pc1 = (4 + hi) ^ (fr & 7);   // ks=1 chunk

  f32x4  acc[8][4] = {};
  bf16x8 af[4][2];     // current mh's A frags [i][ks]
  bf16x8 bfr[4][2];    // current K-tile's B frags [j][ks]

#define STAGE(gptr, ro) do { \
    gload_lds16((gptr) + soff0, lds + (ro) + t*8); \
    gload_lds16((gptr) + soff1, lds + (ro) + 4096 + t*8); \
  } while(0)

#define LDA_(buf, mh) do { \
    const unsigned short* p_ = lds + (buf)*16384 + wm*8192 + (mh)*4096 + fr*64; \
    _Pragma("unroll") for (int i = 0; i < 4; ++i) { \
      af[i][0] = *(const bf16x8*)(p_ + i*1024 + pc0*8); \
      af[i][1] = *(const bf16x8*)(p_ + i*1024 + pc1*8); } \
  } while(0)

#define LDB_(buf, nh) do { \
    const unsigned short* p_ = lds + 32768 + (buf)*16384 + (wn>>1)*8192 + (wn&1)*4096 + fr*64; \
    _Pragma("unroll") for (int jj = 0; jj < 2; ++jj) { \
      bfr[(nh)*2+jj][0] = *(const bf16x8*)(p_ + ((nh)*2+jj)*1024 + pc0*8); \
      bfr[(nh)*2+jj][1] = *(const bf16x8*)(p_ + ((nh)*2+jj)*1024 + pc1*8); } \
  } while(0)

#define MMA_(mh, nh) do { \
    __builtin_amdgcn_s_setprio(1); \
    _Pragma("unroll") for (int i = 0; i < 4; ++i) \
      _Pragma("unroll") for (int jj = 0; jj < 2; ++jj) { \
        acc[(mh)*4+i][(nh)*2+jj] = __builtin_amdgcn_mfma_f32_16x16x32_bf16(af[i][0], bfr[(nh)*2+jj][0], acc[(mh)*4+i][(nh)*2+jj], 0,0,0); \
        acc[(mh)*4+i][(nh)*2+jj] = __builtin_amdgcn_mfma_f32_16x16x32_bf16(af[i][1], bfr[(nh)*2+jj][1], acc[(mh)*4+i][(nh)*2+jj], 0,0,0); } \
    __builtin_amdgcn_s_setprio(0); \
  } while(0)

#define GBAR() __builtin_amdgcn_s_barrier()

  const size_t HSTR = (size_t)128 * K;   // half-tile global row stride
  const int NT = K >> 6;
  const int R  = NT >> 1;

  // prologue: buf0 <- kt0 (all 4 halves), buf1 <- kt1 (B halves only)
  STAGE(Ag,               0);
  STAGE(Ag + HSTR,        8192);
  STAGE(Bg,               32768);
  STAGE(Bg + HSTR,        32768 + 8192);
  STAGE(Bg + 64,          32768 + 16384);
  STAGE(Bg + HSTR + 64,   32768 + 16384 + 8192);
  asm volatile("s_waitcnt vmcnt(4)" ::: "memory");
  GBAR();
  __builtin_amdgcn_sched_barrier(0);

  for (int r = 0; r < R; ++r) {
    const size_t kA1 = (size_t)(2*r + 1) * 64;
    const size_t kN  = (size_t)(2*r + 2) * 64;
    const size_t kN1 = (size_t)(2*r + 3) * 64;
    const bool more = (r + 1 < R);

    // ph0
    LDA_(0, 0); LDB_(0, 0);
    STAGE(Ag + kA1, 16384);
    GBAR(); MMA_(0, 0); GBAR();
    // ph1
    LDB_(0, 1);
    STAGE(Ag + HSTR + kA1, 16384 + 8192);
    GBAR(); MMA_(0, 1); GBAR();
    // ph2
    LDA_(0, 1);
    if (more) STAGE(Bg + kN, 32768);
    GBAR(); MMA_(1, 0); GBAR();
    // ph3
    if (more) STAGE(Bg + HSTR + kN, 32768 + 8192);
    GBAR(); MMA_(1, 1);
    if (more) asm volatile("s_waitcnt vmcnt(4)" ::: "memory");
    else      asm volatile("s_waitcnt vmcnt(0)" ::: "memory");
    GBAR();
    __builtin_amdgcn_sched_barrier(0);
    // ph4
    LDA_(1, 0); LDB_(1, 0);
    if (more) STAGE(Ag + kN, 0);
    GBAR(); MMA_(0, 0); GBAR();
    // ph5
    LDB_(1, 1);
    if (more) STAGE(Ag + HSTR + kN, 8192);
    GBAR(); MMA_(0, 1); GBAR();
    // ph6
    LDA_(1, 1);
    if (more) STAGE(Bg + kN1, 32768 + 16384);
    GBAR(); MMA_(1, 0); GBAR();
    // ph7
    if (more) STAGE(Bg + HSTR + kN1, 32768 + 16384 + 8192);
    GBAR(); MMA_(1, 1);
    if (more) asm volatile("s_waitcnt vmcnt(4)" ::: "memory");
    else      asm volatile("s_waitcnt vmcnt(0)" ::: "memory");
    GBAR();
    __builtin_amdgcn_sched_barrier(0);
  }

  // epilogue: C row = m0 + wm*128 + mi*16 + hi*4 + rr ; col = n0 + wn*64 + j*16 + fr
  const int crow0 = m0 + wm*128 + hi*4;
  const int ccol0 = n0 + wn*64 + fr;
#pragma unroll
  for (int j = 0; j < 4; ++j) {
    const int col = ccol0 + j * 16;
    const float bc = bias[col];
#pragma unroll
    for (int mi = 0; mi < 8; ++mi) {
#pragma unroll
      for (int rr = 0; rr < 4; ++rr) {
        const int row = crow0 + mi * 16 + rr;
        float v = acc[mi][j][rr] + bc;
        if (MODE == 0) {
          if (col < 2048) v = (v > 0.f) ? (v + 1.f) : __expf(v);  // elu(x)+1
          ((unsigned short*)outp)[(size_t)row * N + col] = f2bf(v);
        } else if (MODE == 1) {
          v += addsrc[(size_t)row * N + col];
          ((float*)outp)[(size_t)row * N + col] = v;
        } else {
          v = gelu_f(v);
          ((unsigned short*)outp)[(size_t)row * N + col] = f2bf(v);
        }
      }
    }
  }
#undef STAGE
#undef LDA_
#undef LDB_
#undef MMA_
#undef GBAR
}

// ---------------- per-position head-mix "attention" --------------------------
__global__ void __launch_bounds__(256) attn_kernel(
    const unsigned short* __restrict__ qkv, unsigned short* __restrict__ attn)
{
  __shared__ float sqk[4][2048];
  const int t = threadIdx.x, lane = t & 63, wid = t >> 6;
  const int p = blockIdx.x * 4 + wid;
  const unsigned short* row = qkv + (size_t)p * 3072;
  float* s = sqk[wid];
#pragma unroll
  for (int c = 0; c < 4; ++c) {
    const int idx = c * 512 + lane * 8;
    u16x8 v8 = *(const u16x8*)(row + idx);
#pragma unroll
    for (int u = 0; u < 8; ++u) s[idx + u] = bf2f(v8[u]);
  }
  __syncthreads();

  float vf[16];
#pragma unroll
  for (int g = 0; g < 16; ++g) vf[g] = bf2f(row[2048 + g * 64 + lane]);

  float kv[64] = {};
  float ks[64] = {};
  const float* FK = s + 1024;
#pragma unroll 2
  for (int h = 0; h < 16; ++h) {
    const float vfh = vf[h];
#pragma unroll
    for (int dq = 0; dq < 16; ++dq) {
      const float4 f = *(const float4*)(FK + h * 64 + dq * 4);
      kv[dq*4+0] += f.x * vfh; ks[dq*4+0] += f.x;
      kv[dq*4+1] += f.y * vfh; ks[dq*4+1] += f.y;
      kv[dq*4+2] += f.z * vfh; ks[dq*4+2] += f.z;
      kv[dq*4+3] += f.w * vfh; ks[dq*4+3] += f.w;
    }
  }
  unsigned short* orow = attn + (size_t)p * 1024;
#pragma unroll 2
  for (int h = 0; h < 16; ++h) {
    float aq = 0.f, ak = 0.f;
#pragma unroll
    for (int dq = 0; dq < 16; ++dq) {
      const float4 f = *(const float4*)(s + h * 64 + dq * 4);
      aq += f.x*kv[dq*4+0] + f.y*kv[dq*4+1] + f.z*kv[dq*4+2] + f.w*kv[dq*4+3];
      ak += f.x*ks[dq*4+0] + f.y*ks[dq*4+1] + f.z*ks[dq*4+2] + f.w*ks[dq*4+3];
    }
    orow[h * 64 + lane] = f2bf(aq / (ak + 1e-6f));
  }
}

// ---------------- launch ----------------------------------------------------
extern "C" void kernel_launch(void* const* d_in, const int* in_sizes, int n_in,
                              void* d_out, int out_size, void* d_ws, size_t ws_size,
                              hipStream_t stream) {
  const float* q_x    = (const float*)d_in[0];
  const float* ln1_w  = (const float*)d_in[1];
  const float* ln1_b  = (const float*)d_in[2];
  const float* wq     = (const float*)d_in[3];
  const float* bq     = (const float*)d_in[4];
  const float* wk     = (const float*)d_in[5];
  const float* bk     = (const float*)d_in[6];
  const float* wv     = (const float*)d_in[7];
  const float* bv     = (const float*)d_in[8];
  const float* wo     = (const float*)d_in[9];
  const float* bo     = (const float*)d_in[10];
  const float* ln2_w  = (const float*)d_in[11];
  const float* ln2_b  = (const float*)d_in[12];
  const float* fc_w   = (const float*)d_in[13];
  const float* fc_b   = (const float*)d_in[14];
  const float* proj_w = (const float*)d_in[15];
  const float* proj_b = (const float*)d_in[16];

  char* ws = (char*)d_ws;
  unsigned short* wqkv_t = (unsigned short*)(ws + 0);          //  [3072][1024]
  unsigned short* wo_t   = (unsigned short*)(ws + 6291456);    //  [1024][1024]
  unsigned short* fc_t   = (unsigned short*)(ws + 8388608);    //  [4096][1024]
  unsigned short* proj_t = (unsigned short*)(ws + 16777216);   //  [1024][4096]
  float*          bqkv   = (float*)(ws + 25165824);            //  [3072]
  unsigned short* xn     = (unsigned short*)(ws + 25178112);   //  [16384][1024]
  unsigned short* big    = (unsigned short*)(ws + 58732544);   //  qkv/hg
  float*          xres   = (float*)d_out;

  dim3 blk(256);
  transpose_cvt<<<dim3(32, 32),  blk, 0, stream>>>(wq,     wqkv_t,           1024, 1024);
  transpose_cvt<<<dim3(32, 32),  blk, 0, stream>>>(wk,     wqkv_t + 1048576, 1024, 1024);
  transpose_cvt<<<dim3(32, 32),  blk, 0, stream>>>(wv,     wqkv_t + 2097152, 1024, 1024);
  transpose_cvt<<<dim3(32, 32),  blk, 0, stream>>>(wo,     wo_t,             1024, 1024);
  transpose_cvt<<<dim3(128, 32), blk, 0, stream>>>(fc_w,   fc_t,             1024, 4096);
  transpose_cvt<<<dim3(32, 128), blk, 0, stream>>>(proj_w, proj_t,           4096, 1024);
  concat_bias<<<12, blk, 0, stream>>>(bq, bk, bv, bqkv);

  ln_kernel<<<NTOK, blk, 0, stream>>>(q_x, ln1_w, ln1_b, xn);
  gemm256<0><<<64 * 12, 512, 131072, stream>>>(xn, wqkv_t, NTOK, 3072, 1024, bqkv, nullptr, big);
  attn_kernel<<<NTOK / 4, blk, 0, stream>>>(big, xn);
  gemm256<1><<<64 * 4,  512, 131072, stream>>>(xn, wo_t,   NTOK, 1024, 1024, bo, q_x, xres);
  ln_kernel<<<NTOK, blk, 0, stream>>>(xres, ln2_w, ln2_b, xn);
  gemm256<2><<<64 * 16, 512, 131072, stream>>>(xn, fc_t,   NTOK, 4096, 1024, fc_b, nullptr, big);
  gemm256<1><<<64 * 4,  512, 131072, stream>>>(big, proj_t, NTOK, 1024, 4096, proj_b, xres, xres);
}

// Round 4
// 790.335 us; speedup vs baseline: 1.4766x; 1.2085x over previous
//
#include <hip/hip_runtime.h>
#include <hip/hip_bf16.h>
#include <math.h>

// Problem constants: B=4, N=4096, D=1024, H=16, HD=64, MLP=4096
#define NTOK   16384      // B*N rows
#define DMODEL 1024
#define DMLP   4096

typedef __attribute__((ext_vector_type(8))) __bf16  bf16x8;
typedef __attribute__((ext_vector_type(4))) float   f32x4;
typedef __attribute__((ext_vector_type(8))) unsigned short u16x8;
typedef __attribute__((ext_vector_type(4))) unsigned int   u32x4;

__device__ __forceinline__ float bf2f(unsigned short u) {
  unsigned int i = ((unsigned int)u) << 16;
  return __builtin_bit_cast(float, i);
}
__device__ __forceinline__ unsigned short f2bf(float f) {
  unsigned int u = __builtin_bit_cast(unsigned int, f);
  unsigned int r = 0x7fffu + ((u >> 16) & 1u);
  return (unsigned short)((u + r) >> 16);
}

__device__ __forceinline__ void gload_lds16(const void* g, void* l) {
  __builtin_amdgcn_global_load_lds(
      (const __attribute__((address_space(1))) unsigned int*)g,
      (__attribute__((address_space(3))) unsigned int*)l, 16, 0, 0);
}

__device__ __forceinline__ float gelu_f(float x) {
  float u = 1.5957691216057308f * (x + 0.044715f * x * x * x);
  return x / (1.f + __expf(-u));
}

// attn-output column permutation: c = g(2):r(2):t(2):i(4) -> c' = g:i:r:t
__device__ __forceinline__ int permc(int k) {
  return (k & 0x300) | ((k & 15) << 4) | (((k >> 6) & 3) << 2) | ((k >> 4) & 3);
}
// qkv k/v-block column permutation: n = h*64+d -> n' = d*16+h  (within 1024 block)
__device__ __forceinline__ int kvperm(int n) {
  return ((n & 63) << 4) | ((n >> 6) & 15);
}

// ---------------- weight transpose + f32->bf16 -------------------------------
// PERM: 0 none; 1 = permc on K index (wo); 2 = kvperm on N index (wk/wv)
template<int PERM>
__global__ void __launch_bounds__(256) transpose_cvt(
    const float* __restrict__ W, unsigned short* __restrict__ Wt, int K, int N)
{
  __shared__ float tile[32][33];
  const int kb = blockIdx.y * 32, nb = blockIdx.x * 32;
  const int tx = threadIdx.x & 31, ty = threadIdx.x >> 5;   // 32 x 8
#pragma unroll
  for (int j = 0; j < 32; j += 8)
    tile[ty + j][tx] = W[(size_t)(kb + ty + j) * N + nb + tx];
  __syncthreads();
  const int kw = (PERM == 1) ? permc(kb + tx) : (kb + tx);
#pragma unroll
  for (int j = 0; j < 32; j += 8) {
    const int n  = nb + ty + j;
    const int nw = (PERM == 2) ? kvperm(n) : n;
    Wt[(size_t)nw * K + kw] = f2bf(tile[tx][ty + j]);
  }
}

__global__ void __launch_bounds__(256) concat_bias(
    const float* __restrict__ bq, const float* __restrict__ bk,
    const float* __restrict__ bv, float* __restrict__ bqkv)
{
  const int i = blockIdx.x * 256 + threadIdx.x;   // grid 12 -> 3072
  if (i < 1024)      bqkv[i] = bq[i];
  else if (i < 2048) bqkv[1024 + kvperm(i - 1024)] = bk[i - 1024];
  else               bqkv[2048 + kvperm(i - 2048)] = bv[i - 2048];
}

// ---------------- LayerNorm (biased var, eps=1e-5) -> bf16 -------------------
__global__ void __launch_bounds__(256) ln_kernel(
    const float* __restrict__ x, const float* __restrict__ w,
    const float* __restrict__ b, unsigned short* __restrict__ out)
{
  const int row = blockIdx.x;
  const int t = threadIdx.x;
  const float4 v = ((const float4*)(x + (size_t)row * DMODEL))[t];
  float s  = v.x + v.y + v.z + v.w;
  float s2 = v.x*v.x + v.y*v.y + v.z*v.z + v.w*v.w;
#pragma unroll
  for (int o = 1; o < 64; o <<= 1) { s += __shfl_xor(s, o); s2 += __shfl_xor(s2, o); }
  __shared__ float red[8];
  const int wid = t >> 6;
  if ((t & 63) == 0) { red[wid] = s; red[4 + wid] = s2; }
  __syncthreads();
  s  = red[0] + red[1] + red[2] + red[3];
  s2 = red[4] + red[5] + red[6] + red[7];
  const float mean = s * (1.f / DMODEL);
  const float rstd = rsqrtf(s2 * (1.f / DMODEL) - mean * mean + 1e-5f);
  const float4 wv = ((const float4*)w)[t];
  const float4 bv = ((const float4*)b)[t];
  ushort4 o;
  o.x = f2bf((v.x - mean) * rstd * wv.x + bv.x);
  o.y = f2bf((v.y - mean) * rstd * wv.y + bv.y);
  o.z = f2bf((v.z - mean) * rstd * wv.z + bv.z);
  o.w = f2bf((v.w - mean) * rstd * wv.w + bv.w);
  ((ushort4*)(out + (size_t)row * DMODEL))[t] = o;
}

// ---------------- 256x256 8-phase bf16 MFMA GEMM (unchanged, verified) -------
template<int MODE>
__global__ void __launch_bounds__(512, 2) gemm256(
    const unsigned short* __restrict__ A, const unsigned short* __restrict__ Bt,
    int M, int N, int K,
    const float* __restrict__ bias, const float* __restrict__ addsrc,
    void* __restrict__ outp)
{
  extern __shared__ unsigned short lds[];   // 65536 shorts = 128 KiB
  const int t    = threadIdx.x;
  const int lane = t & 63;
  const int wid  = t >> 6;
  const int wm   = wid >> 2;     // 0..1
  const int wn   = wid & 3;      // 0..3
  const int fr   = lane & 15;
  const int hi   = lane >> 4;    // 0..3

  const int tiles_n = N >> 8;
  const int nwg = (int)gridDim.x;
  const int cpx = nwg >> 3;
  const int bid = (int)blockIdx.x;
  const int wg  = (bid & 7) * cpx + (bid >> 3);
  const int m0 = (wg / tiles_n) << 8;
  const int n0 = (wg % tiles_n) << 8;

  const int srow0 = t >> 3;
  const int srow1 = srow0 + 64;
  const int sc    = t & 7;
  const size_t soff0 = (size_t)srow0 * K + (size_t)((sc ^ (srow0 & 7)) << 3);
  const size_t soff1 = (size_t)srow1 * K + (size_t)((sc ^ (srow1 & 7)) << 3);
  const unsigned short* Ag = A  + (size_t)m0 * K;
  const unsigned short* Bg = Bt + (size_t)n0 * K;

  const int pc0 = hi ^ (fr & 7);         // ks=0 chunk
  const int pc1 = (4 + hi) ^ (fr & 7);   // ks=1 chunk

  f32x4  acc[8][4] = {};
  bf16x8 af[4][2];
  bf16x8 bfr[4][2];

#define STAGE(gptr, ro) do { \
    gload_lds16((gptr) + soff0, lds + (ro) + t*8); \
    gload_lds16((gptr) + soff1, lds + (ro) + 4096 + t*8); \
  } while(0)

#define LDA_(buf, mh) do { \
    const unsigned short* p_ = lds + (buf)*16384 + wm*8192 + (mh)*4096 + fr*64; \
    _Pragma("unroll") for (int i = 0; i < 4; ++i) { \
      af[i][0] = *(const bf16x8*)(p_ + i*1024 + pc0*8); \
      af[i][1] = *(const bf16x8*)(p_ + i*1024 + pc1*8); } \
  } while(0)

#define LDB_(buf, nh) do { \
    const unsigned short* p_ = lds + 32768 + (buf)*16384 + (wn>>1)*8192 + (wn&1)*4096 + fr*64; \
    _Pragma("unroll") for (int jj = 0; jj < 2; ++jj) { \
      bfr[(nh)*2+jj][0] = *(const bf16x8*)(p_ + ((nh)*2+jj)*1024 + pc0*8); \
      bfr[(nh)*2+jj][1] = *(const bf16x8*)(p_ + ((nh)*2+jj)*1024 + pc1*8); } \
  } while(0)

#define MMA_(mh, nh) do { \
    __builtin_amdgcn_s_setprio(1); \
    _Pragma("unroll") for (int i = 0; i < 4; ++i) \
      _Pragma("unroll") for (int jj = 0; jj < 2; ++jj) { \
        acc[(mh)*4+i][(nh)*2+jj] = __builtin_amdgcn_mfma_f32_16x16x32_bf16(af[i][0], bfr[(nh)*2+jj][0], acc[(mh)*4+i][(nh)*2+jj], 0,0,0); \
        acc[(mh)*4+i][(nh)*2+jj] = __builtin_amdgcn_mfma_f32_16x16x32_bf16(af[i][1], bfr[(nh)*2+jj][1], acc[(mh)*4+i][(nh)*2+jj], 0,0,0); } \
    __builtin_amdgcn_s_setprio(0); \
  } while(0)

#define GBAR() __builtin_amdgcn_s_barrier()

  const size_t HSTR = (size_t)128 * K;
  const int NT = K >> 6;
  const int R  = NT >> 1;

  STAGE(Ag,               0);
  STAGE(Ag + HSTR,        8192);
  STAGE(Bg,               32768);
  STAGE(Bg + HSTR,        32768 + 8192);
  STAGE(Bg + 64,          32768 + 16384);
  STAGE(Bg + HSTR + 64,   32768 + 16384 + 8192);
  asm volatile("s_waitcnt vmcnt(4)" ::: "memory");
  GBAR();
  __builtin_amdgcn_sched_barrier(0);

  for (int r = 0; r < R; ++r) {
    const size_t kA1 = (size_t)(2*r + 1) * 64;
    const size_t kN  = (size_t)(2*r + 2) * 64;
    const size_t kN1 = (size_t)(2*r + 3) * 64;
    const bool more = (r + 1 < R);

    LDA_(0, 0); LDB_(0, 0);
    STAGE(Ag + kA1, 16384);
    GBAR(); MMA_(0, 0); GBAR();
    LDB_(0, 1);
    STAGE(Ag + HSTR + kA1, 16384 + 8192);
    GBAR(); MMA_(0, 1); GBAR();
    LDA_(0, 1);
    if (more) STAGE(Bg + kN, 32768);
    GBAR(); MMA_(1, 0); GBAR();
    if (more) STAGE(Bg + HSTR + kN, 32768 + 8192);
    GBAR(); MMA_(1, 1);
    if (more) asm volatile("s_waitcnt vmcnt(4)" ::: "memory");
    else      asm volatile("s_waitcnt vmcnt(0)" ::: "memory");
    GBAR();
    __builtin_amdgcn_sched_barrier(0);
    LDA_(1, 0); LDB_(1, 0);
    if (more) STAGE(Ag + kN, 0);
    GBAR(); MMA_(0, 0); GBAR();
    LDB_(1, 1);
    if (more) STAGE(Ag + HSTR + kN, 8192);
    GBAR(); MMA_(0, 1); GBAR();
    LDA_(1, 1);
    if (more) STAGE(Bg + kN1, 32768 + 16384);
    GBAR(); MMA_(1, 0); GBAR();
    if (more) STAGE(Bg + HSTR + kN1, 32768 + 16384 + 8192);
    GBAR(); MMA_(1, 1);
    if (more) asm volatile("s_waitcnt vmcnt(4)" ::: "memory");
    else      asm volatile("s_waitcnt vmcnt(0)" ::: "memory");
    GBAR();
    __builtin_amdgcn_sched_barrier(0);
  }

  const int crow0 = m0 + wm*128 + hi*4;
  const int ccol0 = n0 + wn*64 + fr;
#pragma unroll
  for (int j = 0; j < 4; ++j) {
    const int col = ccol0 + j * 16;
    const float bc = bias[col];
#pragma unroll
    for (int mi = 0; mi < 8; ++mi) {
#pragma unroll
      for (int rr = 0; rr < 4; ++rr) {
        const int row = crow0 + mi * 16 + rr;
        float v = acc[mi][j][rr] + bc;
        if (MODE == 0) {
          if (col < 2048) v = (v > 0.f) ? (v + 1.f) : __expf(v);  // elu(x)+1
          ((unsigned short*)outp)[(size_t)row * N + col] = f2bf(v);
        } else if (MODE == 1) {
          v += addsrc[(size_t)row * N + col];
          ((float*)outp)[(size_t)row * N + col] = v;
        } else {
          v = gelu_f(v);
          ((unsigned short*)outp)[(size_t)row * N + col] = f2bf(v);
        }
      }
    }
  }
#undef STAGE
#undef LDA_
#undef LDB_
#undef MMA_
#undef GBAR
}

// ---------------- MFMA per-position head-mix "attention" ---------------------
// qkv row (per position, 3072): [0,1024) fq[h][d] (h*64+d);
// [1024,2048) fk^T[d][h] (d*16+h, via kvperm'd weights); [2048,3072) v^T[e][h].
// Stage 1: kv'[d][e'] = sum_h fk[h][d] * V'[h][e'], V' = [v | ones] (e' 0..64).
//   MFMA A = fk^T tile (k=h, zero-padded 16->32 via in-reg mask), B = v^T frag.
// Stage 2: qkv'[h][e'] = sum_d fq[h][d] * kv'[d][e'] (two K=32 MFMAs).
// out[h][e] = qkv'[h][e] / (qkv'[h][64] + 1e-6); stored with column perm
// c' = permc(c) matching the permc-permuted wo_t.
__global__ void __launch_bounds__(256) attn_kernel(
    const unsigned short* __restrict__ qkv, unsigned short* __restrict__ attn)
{
  __shared__ unsigned short kvs[4][16 * 70];  // per-wave kvT, row stride 70
  const int t = threadIdx.x, lane = t & 63, wid = t >> 6;
  const int iL = lane & 15, g = lane >> 4;
  const size_t p = (size_t)blockIdx.x * 4 + wid;
  const unsigned short* row = qkv + p * 3072;
  unsigned short* kvw = kvs[wid] + iL * 70;

  // A1 (fk^T): lane holds A[d_local=iL][k=g*8+j] of tile dt; mask k>=16 lanes
  const unsigned msk = (g < 2) ? 0xFFFFFFFFu : 0u;
  bf16x8 A1[4];
#pragma unroll
  for (int dt = 0; dt < 4; ++dt) {
    u32x4 w = *(const u32x4*)(row + 1024 + (dt * 16 + iL) * 16 + g * 8);
    w.x &= msk; w.y &= msk; w.z &= msk; w.w &= msk;
    A1[dt] = __builtin_bit_cast(bf16x8, w);
  }
  // B1 (v^T): lane holds B[k=g*8+j][col=iL] of e-tile et (k>=16 garbage, A=0)
  bf16x8 B1[4];
#pragma unroll
  for (int et = 0; et < 4; ++et)
    B1[et] = *(const bf16x8*)(row + 2048 + (et * 16 + iL) * 16 + g * 8);
  // fq A-frags: A[h=iL][k=d], k-contiguous
  const unsigned short* fqp = row + iL * 64 + g * 8;
  const bf16x8 aq0 = *(const bf16x8*)(fqp);
  const bf16x8 aq1 = *(const bf16x8*)(fqp + 32);
  // ones column tile (e'=64 at col 0): 1.0 for k<16
  const unsigned ow = (iL == 0 && g < 2) ? 0x3F803F80u : 0u;
  u32x4 onesw = { ow, ow, ow, ow };
  const bf16x8 Bones = __builtin_bit_cast(bf16x8, onesw);

  const f32x4 zf = {0.f, 0.f, 0.f, 0.f};
  f32x4 qacc[5];

#pragma unroll
  for (int et = 0; et < 5; ++et) {
    const bf16x8 Bt1 = (et < 4) ? B1[et] : Bones;
    // stage 1: kv' d-tiles for this e-tile -> kvT[e'_local=iL][d]
#pragma unroll
    for (int dt = 0; dt < 4; ++dt) {
      f32x4 a = __builtin_amdgcn_mfma_f32_16x16x32_bf16(A1[dt], Bt1, zf, 0, 0, 0);
      ushort4 pk;
      pk.x = f2bf(a[0]); pk.y = f2bf(a[1]); pk.z = f2bf(a[2]); pk.w = f2bf(a[3]);
      *(ushort4*)(kvw + dt * 16 + g * 4) = pk;   // d = dt*16 + g*4 + r
    }
    // writes -> reads fence (compiler + HW)
    asm volatile("s_waitcnt lgkmcnt(0)" ::: "memory");
    __builtin_amdgcn_sched_barrier(0);
    // stage 2: B[k=d][col=iL] = kvT[iL][d], contiguous in d
    const bf16x8 b20 = *(const bf16x8*)(kvw + g * 8);
    const bf16x8 b21 = *(const bf16x8*)(kvw + 32 + g * 8);
    f32x4 q = __builtin_amdgcn_mfma_f32_16x16x32_bf16(aq0, b20, zf, 0, 0, 0);
    q       = __builtin_amdgcn_mfma_f32_16x16x32_bf16(aq1, b21, q,  0, 0, 0);
    qacc[et] = q;
    // reads -> next-iteration writes fence
    asm volatile("s_waitcnt lgkmcnt(0)" ::: "memory");
    __builtin_amdgcn_sched_barrier(0);
  }

  // epilogue: lane holds qkv'[h=g*4+r][e'=et*16+iL]; qk at tile 4, lane iL==0
  float inv[4];
#pragma unroll
  for (int r = 0; r < 4; ++r) {
    float qk = __shfl(qacc[4][r], lane & 48);
    float den = qk + 1e-6f;
    float x = __builtin_amdgcn_rcpf(den);
    inv[r] = x * fmaf(-den, x, 2.0f);   // one NR step
  }
  u16x8 o0, o1;
#pragma unroll
  for (int r = 0; r < 4; ++r)
#pragma unroll
    for (int tt = 0; tt < 4; ++tt) {
      const unsigned short b = f2bf(qacc[tt][r] * inv[r]);
      const int idx = r * 4 + tt;      // c' = lane*16 + r*4 + tt
      if (idx < 8) o0[idx] = b; else o1[idx - 8] = b;
    }
  *(u16x8*)(attn + p * 1024 + lane * 16)     = o0;
  *(u16x8*)(attn + p * 1024 + lane * 16 + 8) = o1;
}

// ---------------- launch ----------------------------------------------------
extern "C" void kernel_launch(void* const* d_in, const int* in_sizes, int n_in,
                              void* d_out, int out_size, void* d_ws, size_t ws_size,
                              hipStream_t stream) {
  const float* q_x    = (const float*)d_in[0];
  const float* ln1_w  = (const float*)d_in[1];
  const float* ln1_b  = (const float*)d_in[2];
  const float* wq     = (const float*)d_in[3];
  const float* bq     = (const float*)d_in[4];
  const float* wk     = (const float*)d_in[5];
  const float* bk     = (const float*)d_in[6];
  const float* wv     = (const float*)d_in[7];
  const float* bv     = (const float*)d_in[8];
  const float* wo     = (const float*)d_in[9];
  const float* bo     = (const float*)d_in[10];
  const float* ln2_w  = (const float*)d_in[11];
  const float* ln2_b  = (const float*)d_in[12];
  const float* fc_w   = (const float*)d_in[13];
  const float* fc_b   = (const float*)d_in[14];
  const float* proj_w = (const float*)d_in[15];
  const float* proj_b = (const float*)d_in[16];

  char* ws = (char*)d_ws;
  unsigned short* wqkv_t = (unsigned short*)(ws + 0);          //  [3072][1024]
  unsigned short* wo_t   = (unsigned short*)(ws + 6291456);    //  [1024][1024] (permc'd K)
  unsigned short* fc_t   = (unsigned short*)(ws + 8388608);    //  [4096][1024]
  unsigned short* proj_t = (unsigned short*)(ws + 16777216);   //  [1024][4096]
  float*          bqkv   = (float*)(ws + 25165824);            //  [3072]
  unsigned short* xn     = (unsigned short*)(ws + 25178112);   //  [16384][1024]
  unsigned short* big    = (unsigned short*)(ws + 58732544);   //  qkv/hg
  float*          xres   = (float*)d_out;

  dim3 blk(256);
  transpose_cvt<0><<<dim3(32, 32),  blk, 0, stream>>>(wq,     wqkv_t,           1024, 1024);
  transpose_cvt<2><<<dim3(32, 32),  blk, 0, stream>>>(wk,     wqkv_t + 1048576, 1024, 1024);
  transpose_cvt<2><<<dim3(32, 32),  blk, 0, stream>>>(wv,     wqkv_t + 2097152, 1024, 1024);
  transpose_cvt<1><<<dim3(32, 32),  blk, 0, stream>>>(wo,     wo_t,             1024, 1024);
  transpose_cvt<0><<<dim3(128, 32), blk, 0, stream>>>(fc_w,   fc_t,             1024, 4096);
  transpose_cvt<0><<<dim3(32, 128), blk, 0, stream>>>(proj_w, proj_t,           4096, 1024);
  concat_bias<<<12, blk, 0, stream>>>(bq, bk, bv, bqkv);

  ln_kernel<<<NTOK, blk, 0, stream>>>(q_x, ln1_w, ln1_b, xn);
  gemm256<0><<<64 * 12, 512, 131072, stream>>>(xn, wqkv_t, NTOK, 3072, 1024, bqkv, nullptr, big);
  attn_kernel<<<NTOK / 4, blk, 0, stream>>>(big, xn);
  gemm256<1><<<64 * 4,  512, 131072, stream>>>(xn, wo_t,   NTOK, 1024, 1024, bo, q_x, xres);
  ln_kernel<<<NTOK, blk, 0, stream>>>(xres, ln2_w, ln2_b, xn);
  gemm256<2><<<64 * 16, 512, 131072, stream>>>(xn, fc_t,   NTOK, 4096, 1024, fc_b, nullptr, big);
  gemm256<1><<<64 * 4,  512, 131072, stream>>>(big, proj_t, NTOK, 1024, 4096, proj_b, xres, xres);
}